// Round 1
// 96.127 us; speedup vs baseline: 1.0114x; 1.0114x over previous
//
#include <hip/hip_runtime.h>

// B=32, C=16, RES=128, NA=64
// out[b,0,a,i] = bias + sum_j bilinear(y[b],...), y[b] = sum_c w[c]*x[b,c]
//
// FRONT-END (R10): chanpack now covers 4 rows/block with float4 (16 B/lane)
// x-loads; emits the guarded packed pair-row:
//   pk(p,r,c) = (y0[r-2,c-2], y0[r-2,c-1], y1[r-2,c-2], y1[r-2,c-1]) 4xfp16.
// RADON (R10): unified depth-1 pipeline over the FULL sample descriptor
// (addr, hwx, hwy) — X/Y/floor/frac computed exactly ONCE per j (the R9 code
// computed them twice: addr_of(j+1) + weight recompute at j). Branch-free
// inner loop (clamped stage address is always valid LDS, so the j=128 stage
// is dead-but-safe). Still: ONE ds_read2_b64 + 4 x v_dot2_f32_f16 per pair
// of samples.

#define B_    32
#define C_    16
#define RES   128
#define NA    64
#define SLDS  133              // row stride in 8-B elements (ds_read2_b64 offset1=133 <= 255)
#define ROWS  132
#define NELEM (ROWS * SLDS)    // 17556 elements
#define NPAD  18432            // padded: 18432*8 B = 147456 B = 512 thr * 18 uint4
#define NPAIR 16

typedef _Float16 half2v __attribute__((ext_vector_type(2)));

// ---------------- Kernel 1: fused channel-reduce + guarded pair-pack ----------------
// grid = 16 pairs x 32 row-quads = 512 blocks, 256 threads
// t: u = t>>7 (batch), v = (t>>5)&3 (row in quad), g = t&31 (float4 col group)
__global__ __launch_bounds__(256) void chanpack(const float* __restrict__ x,
                                                const float* __restrict__ w,
                                                uint2* __restrict__ pk) {
    const int blk = blockIdx.x;
    const int p   = blk >> 5;          // pair
    const int qq  = blk & 31;          // row quad
    const int t   = threadIdx.x;
    const int u   = t >> 7;            // batch within pair
    const int v   = (t >> 5) & 3;      // row within quad
    const int g   = t & 31;            // column group (4 floats)

    __shared__ float rowbuf[2][4][130];   // y[k] at [u][v][k+1]; [u][v][0]=[u][v][129]=0

    const float* xb = x + ((size_t)(2 * p + u) * C_) * (RES * RES)
                        + (4 * qq + v) * RES + 4 * g;
    float ax = 0.f, ay = 0.f, az = 0.f, aw = 0.f;
#pragma unroll
    for (int c = 0; c < C_; ++c) {
        const float wc = w[c];
        const float4 xv = *reinterpret_cast<const float4*>(xb + c * (RES * RES));
        ax = fmaf(wc, xv.x, ax);
        ay = fmaf(wc, xv.y, ay);
        az = fmaf(wc, xv.z, az);
        aw = fmaf(wc, xv.w, aw);
    }
    {
        float* rb = &rowbuf[u][v][0];
        rb[4 * g + 1] = ax;
        rb[4 * g + 2] = ay;
        rb[4 * g + 3] = az;
        rb[4 * g + 4] = aw;
        if (g == 0) { rb[0] = 0.f; rb[129] = 0.f; }
    }
    __syncthreads();

    // packed rows r = 4*qq+2 .. 4*qq+5; nonzero for c in [1..129]
    uint2* dst = pk + (size_t)p * NPAD + (4 * qq + 2) * SLDS;

    // main: c in [0..127], 2 rows per pass (v2 = 2*pass + t>>7, c = t&127)
#pragma unroll
    for (int pass = 0; pass < 2; ++pass) {
        const int v2 = 2 * pass + (t >> 7);
        const int c  = t & 127;
        uint2 val = make_uint2(0u, 0u);
        if (c >= 1) {            // c <= 127 < 129 always
            val.x = __builtin_bit_cast(unsigned int,
                        __builtin_amdgcn_cvt_pkrtz(rowbuf[0][v2][c - 1], rowbuf[0][v2][c]));
            val.y = __builtin_bit_cast(unsigned int,
                        __builtin_amdgcn_cvt_pkrtz(rowbuf[1][v2][c - 1], rowbuf[1][v2][c]));
        }
        dst[v2 * SLDS + c] = val;
    }
    // tail: c in [128..132], 4 rows x 5 cols = 20 entries
    if (t < 20) {
        const int v2 = t / 5;
        const int c  = 128 + t % 5;
        uint2 val = make_uint2(0u, 0u);
        if (c <= 129) {          // c=128,129 carry real data; 130..132 zero pad
            val.x = __builtin_bit_cast(unsigned int,
                        __builtin_amdgcn_cvt_pkrtz(rowbuf[0][v2][c - 1], rowbuf[0][v2][c]));
            val.y = __builtin_bit_cast(unsigned int,
                        __builtin_amdgcn_cvt_pkrtz(rowbuf[1][v2][c - 1], rowbuf[1][v2][c]));
        }
        dst[v2 * SLDS + c] = val;
    }

    // qq==0 blocks zero the guard rows (0,1,130,131) and the pad tail
    if (qq == 0) {
        uint2* base = pk + (size_t)p * NPAD;
        const uint2 z = make_uint2(0u, 0u);
        for (int k = t; k < 2 * SLDS; k += 256) {
            base[k] = z;
            base[130 * SLDS + k] = z;
        }
        for (int k = t; k < NPAD - NELEM; k += 256)
            base[NELEM + k] = z;
    }
}

// ---------------- Kernel 2: radon, 2 batches per block ----------------
// grid = 16 pairs x 16 groups = 256 blocks, 512 threads (1 block/CU, 147 KB LDS)
__global__ __launch_bounds__(512) void radon_k(const uint2* __restrict__ pk,
                                               const float* __restrict__ angles,
                                               const float* __restrict__ bias,
                                               float* __restrict__ out) {
    __shared__ uint2 lds[NPAD];   // 147456 B
    const int bid = blockIdx.x;
    const int p   = bid >> 4;
    const int grp = bid & 15;
    const int t   = threadIdx.x;

    const int a = (t >> 7) * 16 + grp;     // wave-uniform angle
    const int i = t & 127;
    const float th = angles[a];            // issue early: latency hides under staging
    const float bv = bias[0];

    // ---- branch-free bulk stage: 18 uint4 per thread, guards included ----
    {
        const uint4* src = (const uint4*)(pk + (size_t)p * NPAD);
        uint4*       dst = (uint4*)lds;
#pragma unroll
        for (int k = 0; k < 18; ++k) dst[k * 512 + t] = src[k * 512 + t];
    }

    // trig + ray setup overlaps the staging drain
    float s, c;
    __sincosf(th, &s, &c);
    const float ci = (float)i - 63.5f;
    const float Xb = fmaf(ci, c, fmaf(63.5f, s, 65.5f));
    const float Yb = fmaf(ci, s, fmaf(-63.5f, c, 65.5f));
    const float ns = -s;

    // packed-fp16 weight constants: uw = pk_fma(h, kM1P1, kP1Z) = (1-w, w)
    const half2v kM1P1 = half2v{(_Float16)(-1.f), (_Float16)(1.f)};
    const half2v kP1Z  = half2v{(_Float16)( 1.f), (_Float16)(0.f)};

    __syncthreads();

    // ---- depth-1 pipeline over the FULL sample descriptor ----
    int    addr;
    half2v hwx, hwy;
    {   // stage j = 0
        const float X  = Xb;
        const float Y  = Yb;
        const float fx = floorf(X), fy = floorf(Y);
        const float gx = fminf(fmaxf(fx, 0.f), 130.f);
        const float gy = fminf(fmaxf(fy, 0.f), 130.f);
        addr = (int)fmaf(gy, (float)SLDS, gx);
        hwx  = __builtin_bit_cast(half2v, __builtin_amdgcn_cvt_pkrtz(X - fx, X - fx));
        hwy  = __builtin_bit_cast(half2v, __builtin_amdgcn_cvt_pkrtz(Y - fy, Y - fy));
    }
    uint2 q0 = lds[addr];
    uint2 q1 = lds[addr + SLDS];

    float acc00 = 0.f, acc01 = 0.f, acc10 = 0.f, acc11 = 0.f;
    float jf = 1.f;

#pragma unroll 8
    for (int j = 0; j < RES; ++j) {
        // ---- stage j+1: X/Y/floor/frac computed exactly once ----
        const float X  = fmaf(jf, ns, Xb);
        const float Y  = fmaf(jf, c,  Yb);
        const float fx = floorf(X), fy = floorf(Y);
        const float wx = X - fx,    wy = Y - fy;
        const float gx = fminf(fmaxf(fx, 0.f), 130.f);
        const float gy = fminf(fmaxf(fy, 0.f), 130.f);
        const int addrn = (int)fmaf(gy, (float)SLDS, gx);   // exact (< 2^24)
        const half2v hwxn = __builtin_bit_cast(half2v, __builtin_amdgcn_cvt_pkrtz(wx, wx));
        const half2v hwyn = __builtin_bit_cast(half2v, __builtin_amdgcn_cvt_pkrtz(wy, wy));
        const uint2 q0n = lds[addrn];          // clamped addr always valid:
        const uint2 q1n = lds[addrn + SLDS];   // j=128 stage is dead-but-safe

        // ---- consume j ----
        const half2v uwx = __builtin_elementwise_fma(hwx, kM1P1, kP1Z);  // (1-wx, wx)
        const half2v uwy = __builtin_elementwise_fma(hwy, kM1P1, kP1Z);  // (1-wy, wy)
        const half2v wa  = uwx * __builtin_shufflevector(uwy, uwy, 0, 0); // *(1-wy)
        const half2v wb  = uwx * __builtin_shufflevector(uwy, uwy, 1, 1); // *wy

        acc00 = __builtin_amdgcn_fdot2(__builtin_bit_cast(half2v, q0.x), wa, acc00, false);
        acc10 = __builtin_amdgcn_fdot2(__builtin_bit_cast(half2v, q0.y), wa, acc10, false);
        acc01 = __builtin_amdgcn_fdot2(__builtin_bit_cast(half2v, q1.x), wb, acc01, false);
        acc11 = __builtin_amdgcn_fdot2(__builtin_bit_cast(half2v, q1.y), wb, acc11, false);

        addr = addrn; hwx = hwxn; hwy = hwyn; q0 = q0n; q1 = q1n;
        jf += 1.f;
    }

    out[(2 * p)     * (NA * RES) + a * RES + i] = (acc00 + acc01) + bv;
    out[(2 * p + 1) * (NA * RES) + a * RES + i] = (acc10 + acc11) + bv;
}

extern "C" void kernel_launch(void* const* d_in, const int* in_sizes, int n_in,
                              void* d_out, int out_size, void* d_ws, size_t ws_size,
                              hipStream_t stream) {
    const float* x      = (const float*)d_in[0];   // 32*16*128*128
    const float* angles = (const float*)d_in[1];   // 64
    const float* w      = (const float*)d_in[2];   // 16
    const float* bias   = (const float*)d_in[3];   // 1
    float* out = (float*)d_out;                    // 32*64*128 fp32

    uint2* pk = (uint2*)d_ws;                      // 16*18432*8 B = 2.36 MiB

    chanpack<<<dim3(NPAIR * 32), dim3(256), 0, stream>>>(x, w, pk);
    radon_k<<<dim3(NPAIR * 16), dim3(512), 0, stream>>>(pk, angles, bias, out);
}